// Round 9
// baseline (600.978 us; speedup 1.0000x reference)
//
#include <hip/hip_runtime.h>
#include <hip/hip_bf16.h>

#define Bb 8
#define Cc 256
#define Nn 4096
#define Dd 32

typedef short bf16x8 __attribute__((ext_vector_type(8)));
typedef short bf16x4 __attribute__((ext_vector_type(4)));
typedef float f32x4 __attribute__((ext_vector_type(4)));

__device__ __forceinline__ void glds16(const void* g, void* l) {
    __builtin_amdgcn_global_load_lds(
        (const __attribute__((address_space(1))) unsigned int*)g,
        (__attribute__((address_space(3))) unsigned int*)l, 16, 0, 0);
}

// ---------------- transpose-convert x -> x_t[b][n][c] bf16, fused stats ----------------
__global__ __launch_bounds__(256) void convt_kernel(
    const float* __restrict__ x, __hip_bfloat16* __restrict__ x_t,
    float* __restrict__ sum_ws, float* __restrict__ sumsq_ws)
{
    __shared__ __hip_bfloat16 tile[64][68];
    const int n0 = blockIdx.x * 64, c0 = blockIdx.y * 64, b = blockIdx.z;
    const int t = threadIdx.x;

#pragma unroll
    for (int i = 0; i < 4; i++) {
        int id = i * 256 + t;
        int row = id >> 4, col4 = id & 15;
        float4 v = *(const float4*)(x + ((size_t)(b * Cc + c0 + row)) * Nn + n0 + col4 * 4);
        bf16x4 bv;
        bv[0] = __bfloat16_as_short(__float2bfloat16(v.x));
        bv[1] = __bfloat16_as_short(__float2bfloat16(v.y));
        bv[2] = __bfloat16_as_short(__float2bfloat16(v.z));
        bv[3] = __bfloat16_as_short(__float2bfloat16(v.w));
        *(bf16x4*)((void*)&tile[row][col4 * 4]) = bv;
        float ls  = v.x + v.y + v.z + v.w;
        float ls2 = v.x * v.x + v.y * v.y + v.z * v.z + v.w * v.w;
        ls  += __shfl_xor(ls, 1, 16);  ls2 += __shfl_xor(ls2, 1, 16);
        ls  += __shfl_xor(ls, 2, 16);  ls2 += __shfl_xor(ls2, 2, 16);
        ls  += __shfl_xor(ls, 4, 16);  ls2 += __shfl_xor(ls2, 4, 16);
        ls  += __shfl_xor(ls, 8, 16);  ls2 += __shfl_xor(ls2, 8, 16);
        if ((t & 15) == 0) {
            atomicAdd(&sum_ws[b * Cc + c0 + row], ls);
            atomicAdd(&sumsq_ws[b * Cc + c0 + row], ls2);
        }
    }
    __syncthreads();
#pragma unroll
    for (int i = 0; i < 2; i++) {
        int id = i * 256 + t;
        int nl = id >> 3, cg = id & 7;
        bf16x8 o;
#pragma unroll
        for (int j = 0; j < 8; j++) o[j] = __bfloat16_as_short(tile[cg * 8 + j][nl]);
        *(bf16x8*)(x_t + ((size_t)(b * Nn + n0 + nl)) * Cc + c0 + cg * 8) = o;
    }
}

// ---------------- W -> bf16 frag-block layout (run once, 5 blocks) ----------------
__global__ __launch_bounds__(256) void wconv_kernel(
    const float* __restrict__ Wq, const float* __restrict__ Wk, const float* __restrict__ Wv,
    __hip_bfloat16* __restrict__ w_bf)
{
    const int ct = blockIdx.x;
    const int t = threadIdx.x;
#pragma unroll
    for (int i = 0; i < 8; i++) {
        int g = i * 256 + t;
        int row = g >> 5, c8 = g & 31;
        int c0 = c8 * 8;
        int grow = ct * 64 + row;
        const float* src;
        if (grow < 32)       src = Wq + (size_t)grow * Cc + c0;
        else if (grow < 64)  src = Wk + (size_t)(grow - 32) * Cc + c0;
        else                 src = Wv + (size_t)(grow - 64) * Cc + c0;
        float4 v0 = *(const float4*)src;
        float4 v1 = *(const float4*)(src + 4);
        bf16x8 o;
        o[0] = __bfloat16_as_short(__float2bfloat16(v0.x));
        o[1] = __bfloat16_as_short(__float2bfloat16(v0.y));
        o[2] = __bfloat16_as_short(__float2bfloat16(v0.z));
        o[3] = __bfloat16_as_short(__float2bfloat16(v0.w));
        o[4] = __bfloat16_as_short(__float2bfloat16(v1.x));
        o[5] = __bfloat16_as_short(__float2bfloat16(v1.y));
        o[6] = __bfloat16_as_short(__float2bfloat16(v1.z));
        o[7] = __bfloat16_as_short(__float2bfloat16(v1.w));
        int kchunk = c0 >> 5, qd = (c0 & 31) >> 3, cg = row >> 4, rl = row & 15;
        *(bf16x8*)(w_bf + ((size_t)ct * 32 + kchunk * 4 + cg) * 512 + (qd * 16 + rl) * 8) = o;
    }
}

// ---------------- MFMA projection (1D grid, b = idx&7 XCD swizzle: x_t 2MB/b
//                  fits one XCD's 4MB L2, so the 5x ct re-reads become L2 hits) ----------------
__global__ __launch_bounds__(256, 2) void proj_kernel(
    const __hip_bfloat16* __restrict__ x_t, const __hip_bfloat16* __restrict__ w_bf,
    const float* __restrict__ bq, const float* __restrict__ bk, const float* __restrict__ bv,
    __hip_bfloat16* __restrict__ q_ws, __hip_bfloat16* __restrict__ k_ws,
    __hip_bfloat16* __restrict__ v_ws)
{
    __shared__ __hip_bfloat16 ldsX[32 * 512];
    __shared__ __hip_bfloat16 ldsW[32 * 512];

    const int b   = blockIdx.x & 7;
    const int id2 = blockIdx.x >> 3;     // 0..319
    const int ct  = id2 >> 6;            // 0..4
    const int n0  = (id2 & 63) * 64;
    const int t = threadIdx.x;
    const int w = t >> 6, lane = t & 63, quad = lane >> 4, l15 = lane & 15;

#pragma unroll
    for (int j = 0; j < 8; j++) {
        int idx = w * 8 + j;
        int kchunk = idx >> 2, ngrp = idx & 3;
        glds16(x_t + ((size_t)(b * Nn + n0 + ngrp * 16 + l15)) * Cc + kchunk * 32 + quad * 8,
               ldsX + idx * 512);
        glds16(w_bf + ((size_t)ct * 32 + idx) * 512 + lane * 8, ldsW + idx * 512);
    }
    __syncthreads();

    f32x4 acc[4];
#pragma unroll
    for (int cg = 0; cg < 4; cg++) {
        int gcol = ct * 64 + cg * 16 + l15;
        float bias = (gcol < 32) ? bq[gcol] : (gcol < 64 ? bk[gcol - 32] : bv[gcol - 64]);
        acc[cg] = (f32x4){bias, bias, bias, bias};
    }

#pragma unroll
    for (int kchunk = 0; kchunk < 8; kchunk++) {
        bf16x8 a = *(const bf16x8*)(ldsX + ((kchunk * 4 + w) * 64 + lane) * 8);
#pragma unroll
        for (int cg = 0; cg < 4; cg++) {
            bf16x8 bw = *(const bf16x8*)(ldsW + ((kchunk * 4 + cg) * 64 + lane) * 8);
            acc[cg] = __builtin_amdgcn_mfma_f32_16x16x32_bf16(a, bw, acc[cg], 0, 0, 0);
        }
    }

#pragma unroll
    for (int cg = 0; cg < 4; cg++) {
        int gcol = ct * 64 + cg * 16 + l15;
        int nb = n0 + w * 16 + quad * 4;
        if (gcol < 64) {
            __hip_bfloat16* dst = (gcol < 32) ? q_ws : k_ws;
            int d = gcol & 31;
#pragma unroll
            for (int r = 0; r < 4; r++)
                dst[((size_t)(b * Nn + nb + r)) * Dd + d] = __float2bfloat16(acc[cg][r]);
        } else {
            int c = gcol - 64;
            bf16x4 o;
#pragma unroll
            for (int r = 0; r < 4; r++) o[r] = __bfloat16_as_short(__float2bfloat16(acc[cg][r]));
            *(bf16x4*)(v_ws + ((size_t)(b * Cc + c)) * Nn + nb) = o;
        }
    }
}

// ---------------- SE gate MLP ----------------
__global__ __launch_bounds__(256) void gate_kernel(
    const float* __restrict__ sum_ws, const float* __restrict__ sumsq_ws,
    const float* __restrict__ W1, const float* __restrict__ W2,
    const float* __restrict__ lamb, float* __restrict__ coef)
{
    int b = blockIdx.x;
    __shared__ float inp[2 * Cc];
    __shared__ float h[32];
    int t = threadIdx.x;
    float s  = sum_ws[b * Cc + t];
    float s2 = sumsq_ws[b * Cc + t];
    float m   = s / Nn;
    float var = (s2 - (float)Nn * m * m) / (float)(Nn - 1);
    inp[t]      = m;
    inp[Cc + t] = sqrtf(fmaxf(var, 0.f));
    __syncthreads();
    if (t < 32) {
        float a = 0.f;
        for (int i = 0; i < 2 * Cc; i++) a += W1[t * (2 * Cc) + i] * inp[i];
        h[t] = fmaxf(a, 0.f);
    }
    __syncthreads();
    float g = 0.f;
#pragma unroll
    for (int r = 0; r < 32; r++) g += W2[t * 32 + r] * h[r];
    float a = 1.f / (1.f + __expf(-g));
    coef[b * Cc + t] = 1.f + lamb[0] * a;
}

// ---------------- flash attention v6: BM=128, 1 barrier/iter, 4mf x 4tcl PV split ----------------
// v5b structure + read-split change: 8 waves -> 2 groups of 4. Wave w accumulates
// m-frags mf0..mf0+3 (mf0=(w>>2)*4) x c-frags tc0..tc0+3 (tc0=(w&3)*4).
// Each ap/bv LDS read now feeds 4 MFMAs -> 20 b128 reads/wave/iter (was 24),
// V redundancy 4->2. acc[4][4]=64 VGPR, safe under (512,2) cap=256 (R4's storm
// came from the (256,4)=64-VGPR cap; R5's from global-load latency — both absent).
// Row-sums: wave w owns mf=w via ap[w&3]·ones; l shared via LDS at epilogue.
__global__ __launch_bounds__(512, 2) void attn_kernel(
    const __hip_bfloat16* __restrict__ q_ws, const __hip_bfloat16* __restrict__ k_ws,
    const __hip_bfloat16* __restrict__ v_ws, const float* __restrict__ coef,
    const float* __restrict__ x, const float* __restrict__ gamma_p,
    float* __restrict__ out)
{
    extern __shared__ __hip_bfloat16 smem[];
    __hip_bfloat16* vbuf0 = smem;              // 16384 el each
    __hip_bfloat16* vbuf1 = smem + 16384;
    __hip_bfloat16* kbuf0 = smem + 32768;      // 4096 el each (8 frags)
    __hip_bfloat16* kbuf1 = smem + 36864;
    __hip_bfloat16* pbuf0 = smem + 40960;      // 8192 el each (16 frags)
    __hip_bfloat16* pbuf1 = smem + 49152;      // total 57344 el = 114688 B

    const int b  = blockIdx.x & 7;             // XCD-locality swizzle
    const int m0 = (blockIdx.x >> 3) * 128;
    const int t = threadIdx.x;
    const int w = t >> 6, lane = t & 63, quad = lane >> 4, l15 = lane & 15;
    const int mf0 = (w >> 2) * 4;              // m-frag group base
    const int tc0 = (w & 3) * 4;               // c-frag base

    // Q A-fragment for m-frag w (S-phase; held all kernel)
    const bf16x8 aq = *(const bf16x8*)(q_ws + ((size_t)(b * Nn + m0 + w * 16 + l15)) * Dd + quad * 8);

    // V staging: wave w stages frags idx = w*4+j (idx = ch*16+tc)
    const __hip_bfloat16* vsrc[4];
#pragma unroll
    for (int j = 0; j < 4; j++) {
        int idx = w * 4 + j;
        int ch = idx >> 4, tc = idx & 15;
        vsrc[j] = v_ws + ((size_t)(b * Cc + tc * 16 + l15)) * Nn + ch * 32 + quad * 8;
    }
    // K staging: slab s = n[128s..128s+128), 8 frags; wave w stages frag w
    const __hip_bfloat16* ksrc = k_ws + ((size_t)(b * Nn + w * 16 + l15)) * Dd + quad * 8;

    // prestage V(0) + K slab 0, then drain before first use (R7 lesson)
#pragma unroll
    for (int j = 0; j < 4; j++) glds16(vsrc[j], vbuf0 + (w * 4 + j) * 512);
    glds16(ksrc, kbuf0 + w * 512);
    __syncthreads();

    f32x4 acc[4][4];
#pragma unroll
    for (int i = 0; i < 4; i++)
#pragma unroll
        for (int j = 0; j < 4; j++) acc[i][j] = (f32x4){0.f, 0.f, 0.f, 0.f};
    f32x4 accl = (f32x4){0.f, 0.f, 0.f, 0.f};

    bf16x8 ones;
#pragma unroll
    for (int i = 0; i < 8; i++) ones[i] = (short)0x3F80;  // bf16 1.0

    for (int it = 0; it < Nn / 64; it++) {
        // ---- S = Q K^T from resident K slab ----
        const __hip_bfloat16* kb = (((it >> 1) & 1) ? kbuf1 : kbuf0) + (it & 1) * 2048;
        f32x4 s[4];
#pragma unroll
        for (int tt = 0; tt < 4; tt++) {
            bf16x8 bk = *(const bf16x8*)(kb + (tt * 64 + lane) * 8);
            s[tt] = __builtin_amdgcn_mfma_f32_16x16x32_bf16(aq, bk, (f32x4){0.f,0.f,0.f,0.f}, 0, 0, 0);
        }
        // ---- P = exp(S) -> frag-block pbuf[it&1] (A-layout for m-frag w) ----
        __hip_bfloat16* pb = (it & 1) ? pbuf1 : pbuf0;
#pragma unroll
        for (int tt = 0; tt < 4; tt++) {
            int nn = (tt & 1) * 16 + l15;
            __hip_bfloat16* pd = pb + (w * 2 + (tt >> 1)) * 512
                               + ((nn >> 3) * 16 + quad * 4) * 8 + (nn & 7);
#pragma unroll
            for (int r = 0; r < 4; r++)
                pd[r * 8] = __float2bfloat16(__expf(s[tt][r]));
        }

        __syncthreads();  // ONE barrier: V(it)/K landed (>=1 iter in flight), P published

        // ---- prefetch next tiles into the other buffers ----
        if (it + 1 < Nn / 64) {
            __hip_bfloat16* vn = ((it + 1) & 1) ? vbuf1 : vbuf0;
#pragma unroll
            for (int j = 0; j < 4; j++)
                glds16(vsrc[j] + (size_t)(it + 1) * 64, vn + (w * 4 + j) * 512);
        }
        if ((it & 1) == 0 && it + 2 < Nn / 64) {
            int sl = (it >> 1) + 1;
            glds16(ksrc + (size_t)(sl * 128) * Dd, ((sl & 1) ? kbuf1 : kbuf0) + w * 512);
        }

        // ---- O += P V ; li += own-row sums ----
        const __hip_bfloat16* vb = (it & 1) ? vbuf1 : vbuf0;
        const __hip_bfloat16* pr = pb;
#pragma unroll
        for (int kc = 0; kc < 2; kc++) {
            bf16x8 ap[4];
#pragma unroll
            for (int i = 0; i < 4; i++)
                ap[i] = *(const bf16x8*)(pr + (((mf0 + i) * 2 + kc) * 64 + lane) * 8);
            accl = __builtin_amdgcn_mfma_f32_16x16x32_bf16(ap[w & 3], ones, accl, 0, 0, 0);
#pragma unroll
            for (int tcl = 0; tcl < 4; tcl++) {
                bf16x8 bv = *(const bf16x8*)(vb + ((kc * 16 + tc0 + tcl) * 64 + lane) * 8);
#pragma unroll
                for (int i = 0; i < 4; i++)
                    acc[i][tcl] = __builtin_amdgcn_mfma_f32_16x16x32_bf16(ap[i], bv, acc[i][tcl], 0, 0, 0);
            }
        }
    }

    // ---- share l across waves (wave w owns rows of mf=w) ----
    float* ldsL = (float*)smem;
    __syncthreads();
    if (l15 == 0) {
#pragma unroll
        for (int r = 0; r < 4; r++) ldsL[w * 16 + quad * 4 + r] = accl[r];
    }
    __syncthreads();

    const float g = gamma_p[0];
    f32x4 inv[4];
#pragma unroll
    for (int i = 0; i < 4; i++) {
        f32x4 lr = *(const f32x4*)(ldsL + (mf0 + i) * 16 + quad * 4);
#pragma unroll
        for (int r = 0; r < 4; r++) inv[i][r] = g / lr[r];
    }

#pragma unroll
    for (int i = 0; i < 4; i++) {
#pragma unroll
        for (int tcl = 0; tcl < 4; tcl++) {
            int c = (tc0 + tcl) * 16 + l15;
            float cf = coef[b * Cc + c];
            size_t base = ((size_t)(b * Cc + c)) * Nn + m0 + (mf0 + i) * 16 + quad * 4;
#pragma unroll
            for (int r = 0; r < 4; r++)
                out[base + r] = acc[i][tcl][r] * inv[i][r] + cf * x[base + r];
        }
    }
}

extern "C" void kernel_launch(void* const* d_in, const int* in_sizes, int n_in,
                              void* d_out, int out_size, void* d_ws, size_t ws_size,
                              hipStream_t stream) {
    const float* x     = (const float*)d_in[0];
    const float* Wq    = (const float*)d_in[1];
    const float* bq    = (const float*)d_in[2];
    const float* Wk    = (const float*)d_in[3];
    const float* bk    = (const float*)d_in[4];
    const float* Wv    = (const float*)d_in[5];
    const float* bv    = (const float*)d_in[6];
    const float* gamma = (const float*)d_in[7];
    const float* W1    = (const float*)d_in[8];
    const float* W2    = (const float*)d_in[9];
    const float* lamb  = (const float*)d_in[10];
    float* out = (float*)d_out;

    char* ws = (char*)d_ws;
    __hip_bfloat16* q_ws = (__hip_bfloat16*)ws;                       //  2 MB
    __hip_bfloat16* k_ws = (__hip_bfloat16*)(ws + (2u  << 20));       //  2 MB
    __hip_bfloat16* v_ws = (__hip_bfloat16*)(ws + (4u  << 20));       // 16 MB
    __hip_bfloat16* x_t  = (__hip_bfloat16*)(ws + (20u << 20));       // 16 MB
    float* sum_ws   = (float*)(ws + (36u << 20));
    float* sumsq_ws = sum_ws + Bb * Cc;
    float* coef     = sumsq_ws + Bb * Cc;
    __hip_bfloat16* w_bf = (__hip_bfloat16*)(ws + (37u << 20));       // 320 KB

    (void)hipFuncSetAttribute((const void*)attn_kernel,
                              hipFuncAttributeMaxDynamicSharedMemorySize, 114688);

    hipMemsetAsync(sum_ws, 0, 2 * Bb * Cc * sizeof(float), stream);
    wconv_kernel<<<5, 256, 0, stream>>>(Wq, Wk, Wv, w_bf);
    convt_kernel<<<dim3(Nn / 64, Cc / 64, Bb), 256, 0, stream>>>(x, x_t, sum_ws, sumsq_ws);
    proj_kernel<<<Bb * 5 * (Nn / 64), 256, 0, stream>>>(x_t, w_bf, bq, bk, bv, q_ws, k_ws, v_ws);
    gate_kernel<<<Bb, 256, 0, stream>>>(sum_ws, sumsq_ws, W1, W2, lamb, coef);
    attn_kernel<<<256, 512, 114688, stream>>>(q_ws, k_ws, v_ws, coef, x, gamma, out);
}

// Round 10
// 246.920 us; speedup vs baseline: 2.4339x; 2.4339x over previous
//
#include <hip/hip_runtime.h>
#include <hip/hip_bf16.h>

#define Bb 8
#define Cc 256
#define Nn 4096
#define Dd 32

typedef short bf16x8 __attribute__((ext_vector_type(8)));
typedef short bf16x4 __attribute__((ext_vector_type(4)));
typedef float f32x4 __attribute__((ext_vector_type(4)));

__device__ __forceinline__ void glds16(const void* g, void* l) {
    __builtin_amdgcn_global_load_lds(
        (const __attribute__((address_space(1))) unsigned int*)g,
        (__attribute__((address_space(3))) unsigned int*)l, 16, 0, 0);
}

// ---------------- transpose-convert x -> x_t[b][n][c] bf16, fused stats ----------------
__global__ __launch_bounds__(256) void convt_kernel(
    const float* __restrict__ x, __hip_bfloat16* __restrict__ x_t,
    float* __restrict__ sum_ws, float* __restrict__ sumsq_ws)
{
    __shared__ __hip_bfloat16 tile[64][68];
    const int n0 = blockIdx.x * 64, c0 = blockIdx.y * 64, b = blockIdx.z;
    const int t = threadIdx.x;

#pragma unroll
    for (int i = 0; i < 4; i++) {
        int id = i * 256 + t;
        int row = id >> 4, col4 = id & 15;
        float4 v = *(const float4*)(x + ((size_t)(b * Cc + c0 + row)) * Nn + n0 + col4 * 4);
        bf16x4 bv;
        bv[0] = __bfloat16_as_short(__float2bfloat16(v.x));
        bv[1] = __bfloat16_as_short(__float2bfloat16(v.y));
        bv[2] = __bfloat16_as_short(__float2bfloat16(v.z));
        bv[3] = __bfloat16_as_short(__float2bfloat16(v.w));
        *(bf16x4*)((void*)&tile[row][col4 * 4]) = bv;
        float ls  = v.x + v.y + v.z + v.w;
        float ls2 = v.x * v.x + v.y * v.y + v.z * v.z + v.w * v.w;
        ls  += __shfl_xor(ls, 1, 16);  ls2 += __shfl_xor(ls2, 1, 16);
        ls  += __shfl_xor(ls, 2, 16);  ls2 += __shfl_xor(ls2, 2, 16);
        ls  += __shfl_xor(ls, 4, 16);  ls2 += __shfl_xor(ls2, 4, 16);
        ls  += __shfl_xor(ls, 8, 16);  ls2 += __shfl_xor(ls2, 8, 16);
        if ((t & 15) == 0) {
            atomicAdd(&sum_ws[b * Cc + c0 + row], ls);
            atomicAdd(&sumsq_ws[b * Cc + c0 + row], ls2);
        }
    }
    __syncthreads();
#pragma unroll
    for (int i = 0; i < 2; i++) {
        int id = i * 256 + t;
        int nl = id >> 3, cg = id & 7;
        bf16x8 o;
#pragma unroll
        for (int j = 0; j < 8; j++) o[j] = __bfloat16_as_short(tile[cg * 8 + j][nl]);
        *(bf16x8*)(x_t + ((size_t)(b * Nn + n0 + nl)) * Cc + c0 + cg * 8) = o;
    }
}

// ---------------- W -> bf16 frag-block layout (run once, 5 blocks) ----------------
__global__ __launch_bounds__(256) void wconv_kernel(
    const float* __restrict__ Wq, const float* __restrict__ Wk, const float* __restrict__ Wv,
    __hip_bfloat16* __restrict__ w_bf)
{
    const int ct = blockIdx.x;
    const int t = threadIdx.x;
#pragma unroll
    for (int i = 0; i < 8; i++) {
        int g = i * 256 + t;
        int row = g >> 5, c8 = g & 31;
        int c0 = c8 * 8;
        int grow = ct * 64 + row;
        const float* src;
        if (grow < 32)       src = Wq + (size_t)grow * Cc + c0;
        else if (grow < 64)  src = Wk + (size_t)(grow - 32) * Cc + c0;
        else                 src = Wv + (size_t)(grow - 64) * Cc + c0;
        float4 v0 = *(const float4*)src;
        float4 v1 = *(const float4*)(src + 4);
        bf16x8 o;
        o[0] = __bfloat16_as_short(__float2bfloat16(v0.x));
        o[1] = __bfloat16_as_short(__float2bfloat16(v0.y));
        o[2] = __bfloat16_as_short(__float2bfloat16(v0.z));
        o[3] = __bfloat16_as_short(__float2bfloat16(v0.w));
        o[4] = __bfloat16_as_short(__float2bfloat16(v1.x));
        o[5] = __bfloat16_as_short(__float2bfloat16(v1.y));
        o[6] = __bfloat16_as_short(__float2bfloat16(v1.z));
        o[7] = __bfloat16_as_short(__float2bfloat16(v1.w));
        int kchunk = c0 >> 5, qd = (c0 & 31) >> 3, cg = row >> 4, rl = row & 15;
        *(bf16x8*)(w_bf + ((size_t)ct * 32 + kchunk * 4 + cg) * 512 + (qd * 16 + rl) * 8) = o;
    }
}

// ---------------- MFMA projection (1D grid, b = idx&7 XCD swizzle) ----------------
__global__ __launch_bounds__(256, 2) void proj_kernel(
    const __hip_bfloat16* __restrict__ x_t, const __hip_bfloat16* __restrict__ w_bf,
    const float* __restrict__ bq, const float* __restrict__ bk, const float* __restrict__ bv,
    __hip_bfloat16* __restrict__ q_ws, __hip_bfloat16* __restrict__ k_ws,
    __hip_bfloat16* __restrict__ v_ws)
{
    __shared__ __hip_bfloat16 ldsX[32 * 512];
    __shared__ __hip_bfloat16 ldsW[32 * 512];

    const int b   = blockIdx.x & 7;
    const int id2 = blockIdx.x >> 3;     // 0..319
    const int ct  = id2 >> 6;            // 0..4
    const int n0  = (id2 & 63) * 64;
    const int t = threadIdx.x;
    const int w = t >> 6, lane = t & 63, quad = lane >> 4, l15 = lane & 15;

#pragma unroll
    for (int j = 0; j < 8; j++) {
        int idx = w * 8 + j;
        int kchunk = idx >> 2, ngrp = idx & 3;
        glds16(x_t + ((size_t)(b * Nn + n0 + ngrp * 16 + l15)) * Cc + kchunk * 32 + quad * 8,
               ldsX + idx * 512);
        glds16(w_bf + ((size_t)ct * 32 + idx) * 512 + lane * 8, ldsW + idx * 512);
    }
    __syncthreads();

    f32x4 acc[4];
#pragma unroll
    for (int cg = 0; cg < 4; cg++) {
        int gcol = ct * 64 + cg * 16 + l15;
        float bias = (gcol < 32) ? bq[gcol] : (gcol < 64 ? bk[gcol - 32] : bv[gcol - 64]);
        acc[cg] = (f32x4){bias, bias, bias, bias};
    }

#pragma unroll
    for (int kchunk = 0; kchunk < 8; kchunk++) {
        bf16x8 a = *(const bf16x8*)(ldsX + ((kchunk * 4 + w) * 64 + lane) * 8);
#pragma unroll
        for (int cg = 0; cg < 4; cg++) {
            bf16x8 bw = *(const bf16x8*)(ldsW + ((kchunk * 4 + cg) * 64 + lane) * 8);
            acc[cg] = __builtin_amdgcn_mfma_f32_16x16x32_bf16(a, bw, acc[cg], 0, 0, 0);
        }
    }

#pragma unroll
    for (int cg = 0; cg < 4; cg++) {
        int gcol = ct * 64 + cg * 16 + l15;
        int nb = n0 + w * 16 + quad * 4;
        if (gcol < 64) {
            __hip_bfloat16* dst = (gcol < 32) ? q_ws : k_ws;
            int d = gcol & 31;
#pragma unroll
            for (int r = 0; r < 4; r++)
                dst[((size_t)(b * Nn + nb + r)) * Dd + d] = __float2bfloat16(acc[cg][r]);
        } else {
            int c = gcol - 64;
            bf16x4 o;
#pragma unroll
            for (int r = 0; r < 4; r++) o[r] = __bfloat16_as_short(__float2bfloat16(acc[cg][r]));
            *(bf16x4*)(v_ws + ((size_t)(b * Cc + c)) * Nn + nb) = o;
        }
    }
}

// ---------------- SE gate MLP ----------------
__global__ __launch_bounds__(256) void gate_kernel(
    const float* __restrict__ sum_ws, const float* __restrict__ sumsq_ws,
    const float* __restrict__ W1, const float* __restrict__ W2,
    const float* __restrict__ lamb, float* __restrict__ coef)
{
    int b = blockIdx.x;
    __shared__ float inp[2 * Cc];
    __shared__ float h[32];
    int t = threadIdx.x;
    float s  = sum_ws[b * Cc + t];
    float s2 = sumsq_ws[b * Cc + t];
    float m   = s / Nn;
    float var = (s2 - (float)Nn * m * m) / (float)(Nn - 1);
    inp[t]      = m;
    inp[Cc + t] = sqrtf(fmaxf(var, 0.f));
    __syncthreads();
    if (t < 32) {
        float a = 0.f;
        for (int i = 0; i < 2 * Cc; i++) a += W1[t * (2 * Cc) + i] * inp[i];
        h[t] = fmaxf(a, 0.f);
    }
    __syncthreads();
    float g = 0.f;
#pragma unroll
    for (int r = 0; r < 32; r++) g += W2[t * 32 + r] * h[r];
    float a = 1.f / (1.f + __expf(-g));
    coef[b * Cc + t] = 1.f + lamb[0] * a;
}

// ---------------- flash attention v7: 4mf x 4tcl split, ZERO runtime reg indexing ----------------
// R9's storm root cause: ap[w&3] runtime index -> compiler demotes ap[] to
// scratch -> VALUBusy 77%. (R4 had the same construct, ap[w].) v7: all ap uses
// statically unrolled; row-sums accl4[i] computed for ALL 4 owned m-frags via
// static ones-MFMAs (8/iter, +29cyc) -> no select, no epilogue LDS share.
// LDS reads/wave/iter: 24 -> 20 b128 (V redundancy 4->2).
__global__ __launch_bounds__(512, 2) void attn_kernel(
    const __hip_bfloat16* __restrict__ q_ws, const __hip_bfloat16* __restrict__ k_ws,
    const __hip_bfloat16* __restrict__ v_ws, const float* __restrict__ coef,
    const float* __restrict__ x, const float* __restrict__ gamma_p,
    float* __restrict__ out)
{
    extern __shared__ __hip_bfloat16 smem[];
    __hip_bfloat16* vbuf0 = smem;              // 16384 el each
    __hip_bfloat16* vbuf1 = smem + 16384;
    __hip_bfloat16* kbuf0 = smem + 32768;      // 4096 el each (8 frags)
    __hip_bfloat16* kbuf1 = smem + 36864;
    __hip_bfloat16* pbuf0 = smem + 40960;      // 8192 el each (16 frags)
    __hip_bfloat16* pbuf1 = smem + 49152;      // total 57344 el = 114688 B

    const int b  = blockIdx.x & 7;             // XCD-locality swizzle
    const int m0 = (blockIdx.x >> 3) * 128;
    const int t = threadIdx.x;
    const int w = t >> 6, lane = t & 63, quad = lane >> 4, l15 = lane & 15;
    const int mf0 = (w >> 2) * 4;              // m-frag group base (0 or 4)
    const int tc0 = (w & 3) * 4;               // c-frag base (0,4,8,12)

    // Q A-fragment for m-frag w (S-phase; held all kernel)
    const bf16x8 aq = *(const bf16x8*)(q_ws + ((size_t)(b * Nn + m0 + w * 16 + l15)) * Dd + quad * 8);

    // V staging: wave w stages frags idx = w*4+j (idx = ch*16+tc)
    const __hip_bfloat16* vsrc[4];
#pragma unroll
    for (int j = 0; j < 4; j++) {
        int idx = w * 4 + j;
        int ch = idx >> 4, tc = idx & 15;
        vsrc[j] = v_ws + ((size_t)(b * Cc + tc * 16 + l15)) * Nn + ch * 32 + quad * 8;
    }
    // K staging: slab s = n[128s..128s+128), 8 frags; wave w stages frag w
    const __hip_bfloat16* ksrc = k_ws + ((size_t)(b * Nn + w * 16 + l15)) * Dd + quad * 8;

    // prestage V(0) + K slab 0, then drain before first use (R7 lesson)
#pragma unroll
    for (int j = 0; j < 4; j++) glds16(vsrc[j], vbuf0 + (w * 4 + j) * 512);
    glds16(ksrc, kbuf0 + w * 512);
    __syncthreads();

    f32x4 acc[4][4];
#pragma unroll
    for (int i = 0; i < 4; i++)
#pragma unroll
        for (int j = 0; j < 4; j++) acc[i][j] = (f32x4){0.f, 0.f, 0.f, 0.f};
    f32x4 accl4[4];
#pragma unroll
    for (int i = 0; i < 4; i++) accl4[i] = (f32x4){0.f, 0.f, 0.f, 0.f};

    bf16x8 ones;
#pragma unroll
    for (int i = 0; i < 8; i++) ones[i] = (short)0x3F80;  // bf16 1.0

    for (int it = 0; it < Nn / 64; it++) {
        // ---- S = Q K^T from resident K slab ----
        const __hip_bfloat16* kb = (((it >> 1) & 1) ? kbuf1 : kbuf0) + (it & 1) * 2048;
        f32x4 s[4];
#pragma unroll
        for (int tt = 0; tt < 4; tt++) {
            bf16x8 bk = *(const bf16x8*)(kb + (tt * 64 + lane) * 8);
            s[tt] = __builtin_amdgcn_mfma_f32_16x16x32_bf16(aq, bk, (f32x4){0.f,0.f,0.f,0.f}, 0, 0, 0);
        }
        // ---- P = exp(S) -> frag-block pbuf[it&1] (A-layout for m-frag w) ----
        __hip_bfloat16* pb = (it & 1) ? pbuf1 : pbuf0;
#pragma unroll
        for (int tt = 0; tt < 4; tt++) {
            int nn = (tt & 1) * 16 + l15;
            __hip_bfloat16* pd = pb + (w * 2 + (tt >> 1)) * 512
                               + ((nn >> 3) * 16 + quad * 4) * 8 + (nn & 7);
#pragma unroll
            for (int r = 0; r < 4; r++)
                pd[r * 8] = __float2bfloat16(__expf(s[tt][r]));
        }

        __syncthreads();  // ONE barrier: V(it)/K landed (>=1 iter in flight), P published

        // ---- prefetch next tiles into the other buffers ----
        if (it + 1 < Nn / 64) {
            __hip_bfloat16* vn = ((it + 1) & 1) ? vbuf1 : vbuf0;
#pragma unroll
            for (int j = 0; j < 4; j++)
                glds16(vsrc[j] + (size_t)(it + 1) * 64, vn + (w * 4 + j) * 512);
        }
        if ((it & 1) == 0 && it + 2 < Nn / 64) {
            int sl = (it >> 1) + 1;
            glds16(ksrc + (size_t)(sl * 128) * Dd, ((sl & 1) ? kbuf1 : kbuf0) + w * 512);
        }

        // ---- O += P V ; row-sums for all 4 owned m-frags (all static) ----
        const __hip_bfloat16* vb = (it & 1) ? vbuf1 : vbuf0;
        const __hip_bfloat16* pr = pb;
#pragma unroll
        for (int kc = 0; kc < 2; kc++) {
            bf16x8 ap0 = *(const bf16x8*)(pr + (((mf0 + 0) * 2 + kc) * 64 + lane) * 8);
            bf16x8 ap1 = *(const bf16x8*)(pr + (((mf0 + 1) * 2 + kc) * 64 + lane) * 8);
            bf16x8 ap2 = *(const bf16x8*)(pr + (((mf0 + 2) * 2 + kc) * 64 + lane) * 8);
            bf16x8 ap3 = *(const bf16x8*)(pr + (((mf0 + 3) * 2 + kc) * 64 + lane) * 8);
            accl4[0] = __builtin_amdgcn_mfma_f32_16x16x32_bf16(ap0, ones, accl4[0], 0, 0, 0);
            accl4[1] = __builtin_amdgcn_mfma_f32_16x16x32_bf16(ap1, ones, accl4[1], 0, 0, 0);
            accl4[2] = __builtin_amdgcn_mfma_f32_16x16x32_bf16(ap2, ones, accl4[2], 0, 0, 0);
            accl4[3] = __builtin_amdgcn_mfma_f32_16x16x32_bf16(ap3, ones, accl4[3], 0, 0, 0);
#pragma unroll
            for (int tcl = 0; tcl < 4; tcl++) {
                bf16x8 bv = *(const bf16x8*)(vb + ((kc * 16 + tc0 + tcl) * 64 + lane) * 8);
                acc[0][tcl] = __builtin_amdgcn_mfma_f32_16x16x32_bf16(ap0, bv, acc[0][tcl], 0, 0, 0);
                acc[1][tcl] = __builtin_amdgcn_mfma_f32_16x16x32_bf16(ap1, bv, acc[1][tcl], 0, 0, 0);
                acc[2][tcl] = __builtin_amdgcn_mfma_f32_16x16x32_bf16(ap2, bv, acc[2][tcl], 0, 0, 0);
                acc[3][tcl] = __builtin_amdgcn_mfma_f32_16x16x32_bf16(ap3, bv, acc[3][tcl], 0, 0, 0);
            }
        }
    }

    // ---- epilogue: out = gamma*O/l + (1 + lamb*a)*x ; l is lane-local in accl4 ----
    const float g = gamma_p[0];
    f32x4 inv[4];
#pragma unroll
    for (int i = 0; i < 4; i++) {
#pragma unroll
        for (int r = 0; r < 4; r++) inv[i][r] = g / accl4[i][r];
    }

#pragma unroll
    for (int i = 0; i < 4; i++) {
#pragma unroll
        for (int tcl = 0; tcl < 4; tcl++) {
            int c = (tc0 + tcl) * 16 + l15;
            float cf = coef[b * Cc + c];
            size_t base = ((size_t)(b * Cc + c)) * Nn + m0 + (mf0 + i) * 16 + quad * 4;
#pragma unroll
            for (int r = 0; r < 4; r++)
                out[base + r] = acc[i][tcl][r] * inv[i][r] + cf * x[base + r];
        }
    }
}

extern "C" void kernel_launch(void* const* d_in, const int* in_sizes, int n_in,
                              void* d_out, int out_size, void* d_ws, size_t ws_size,
                              hipStream_t stream) {
    const float* x     = (const float*)d_in[0];
    const float* Wq    = (const float*)d_in[1];
    const float* bq    = (const float*)d_in[2];
    const float* Wk    = (const float*)d_in[3];
    const float* bk    = (const float*)d_in[4];
    const float* Wv    = (const float*)d_in[5];
    const float* bv    = (const float*)d_in[6];
    const float* gamma = (const float*)d_in[7];
    const float* W1    = (const float*)d_in[8];
    const float* W2    = (const float*)d_in[9];
    const float* lamb  = (const float*)d_in[10];
    float* out = (float*)d_out;

    char* ws = (char*)d_ws;
    __hip_bfloat16* q_ws = (__hip_bfloat16*)ws;                       //  2 MB
    __hip_bfloat16* k_ws = (__hip_bfloat16*)(ws + (2u  << 20));       //  2 MB
    __hip_bfloat16* v_ws = (__hip_bfloat16*)(ws + (4u  << 20));       // 16 MB
    __hip_bfloat16* x_t  = (__hip_bfloat16*)(ws + (20u << 20));       // 16 MB
    float* sum_ws   = (float*)(ws + (36u << 20));
    float* sumsq_ws = sum_ws + Bb * Cc;
    float* coef     = sumsq_ws + Bb * Cc;
    __hip_bfloat16* w_bf = (__hip_bfloat16*)(ws + (37u << 20));       // 320 KB

    (void)hipFuncSetAttribute((const void*)attn_kernel,
                              hipFuncAttributeMaxDynamicSharedMemorySize, 114688);

    hipMemsetAsync(sum_ws, 0, 2 * Bb * Cc * sizeof(float), stream);
    wconv_kernel<<<5, 256, 0, stream>>>(Wq, Wk, Wv, w_bf);
    convt_kernel<<<dim3(Nn / 64, Cc / 64, Bb), 256, 0, stream>>>(x, x_t, sum_ws, sumsq_ws);
    proj_kernel<<<Bb * 5 * (Nn / 64), 256, 0, stream>>>(x_t, w_bf, bq, bk, bv, q_ws, k_ws, v_ws);
    gate_kernel<<<Bb, 256, 0, stream>>>(sum_ws, sumsq_ws, W1, W2, lamb, coef);
    attn_kernel<<<256, 512, 114688, stream>>>(q_ws, k_ws, v_ws, coef, x, gamma, out);
}